// Round 8
// baseline (81.950 us; speedup 1.0000x reference)
//
#include <hip/hip_runtime.h>

#define N_VIEWS 5
#define N_JOINTS 15
#define HM_H 128
#define HM_W 240
#define PB 4
#define VXn 64
#define VYn 64
#define VZn 64
#define FXn 253
#define FYn 253
#define FZn 64
#define JP 16   // joints padded to 16 -> one 16B load per tap

typedef float        vf2 __attribute__((ext_vector_type(2)));
typedef unsigned int vu4 __attribute__((ext_vector_type(4)));
typedef int          vi4 __attribute__((ext_vector_type(4)));

#define T_TOTAL (N_VIEWS * HM_H * HM_W)     // 153600
#define G_TOTAL (3 * 4096)                  // 12288
#define TABLE_BYTES (T_TOTAL * JP)          // 2457600

#if defined(__has_builtin)
#if __has_builtin(__builtin_amdgcn_make_buffer_rsrc) && __has_builtin(__builtin_amdgcn_raw_ptr_buffer_load_b128)
#define USE_BUFLOAD 1
#endif
#endif

// ---------------------------------------------------------------------------
// Kernel 1: transpose+quantize heatmaps (V,J,H,W) f32 -> (V,H,W,16) u8,
// with the constant grids output fused into trailing blocks.
// ---------------------------------------------------------------------------
__global__ void prep_kernel(const float* __restrict__ hm,
                            unsigned char* __restrict__ T,
                            float* __restrict__ gout) {
    int t = blockIdx.x * blockDim.x + threadIdx.x;
    if (t < T_TOTAL) {
        int x = t % HM_W;
        int vy = t / HM_W;
        int y = vy % HM_H;
        int v = vy / HM_H;
        unsigned int w[4] = {0u, 0u, 0u, 0u};
#pragma unroll
        for (int j = 0; j < N_JOINTS; ++j) {
            float val = hm[(((size_t)v * N_JOINTS + j) * HM_H + y) * HM_W + x];
            float q = rintf(val * 255.0f);
            q = fminf(fmaxf(q, 0.0f), 255.0f);
            w[j >> 2] |= ((unsigned int)q) << ((j & 3) * 8);
        }
        vu4* dst = (vu4*)(T + (size_t)t * JP);
        vu4 o; o.x = w[0]; o.y = w[1]; o.z = w[2]; o.w = w[3];
        *dst = o;
    } else {
        int u = t - T_TOTAL;
        if (u >= G_TOTAL) return;
        int g = u / 4096;
        int idx = u % 4096;
        int a = idx / 64;
        int b = idx % 64;
        const float step = 2000.0f / 63.0f;
        float va = -1000.0f + (float)a * step;
        float vb = -1000.0f + (float)b * step;
        float o0, o1;
        if (g == 0)      { o0 = va + 0.0f;      o1 = vb + (-500.0f); }
        else if (g == 1) { o0 = va + 0.0f;      o1 = vb + 800.0f;    }
        else             { o0 = va + (-500.0f); o1 = vb + 800.0f;    }
        gout[(size_t)u * 2 + 0] = o0;
        gout[(size_t)u * 2 + 1] = o1;
    }
}

// ---------------------------------------------------------------------------
// Kernel 2: main projection — exact R3 geometry (best measured: 63.4 us),
// with ONE change: tap loads use buffer_load_dwordx4 with aux=GLC->sc0,
// which bypasses the 32KB vector L1 (which the 2.46MB table thrashes) and
// serves taps directly from the XCD L2. Single-variable experiment.
// block = 128 (2 waves: lane = iz). grid = (32, 64, 4).
// ---------------------------------------------------------------------------
__global__ __launch_bounds__(128) void project_kernel(
    const unsigned char* __restrict__ hmT, // (V,H,W,16) u8, 2.46 MB
    const float* __restrict__ sg,          // (V,FX,FY,FZ,2)
    const float* __restrict__ pc,          // (P,7)
    float* __restrict__ out)               // (P,J,VX,VY,VZ)
{
    const int iz = threadIdx.x & 63;                        // 0..63
    const int iy = blockIdx.x * 2 + (threadIdx.x >> 6);     // 0..63
    const int ix = blockIdx.y;                              // 0..63
    const int p  = blockIdx.z;                              // 0..3

    // ---- per-proposal scalars (wave-uniform) ----
    const float pw = pc[p * 7 + 5];
    const float ph = pc[p * 7 + 6];
    int mask_x = max((int)((1.0f - pw) / 2.0f * (float)(VXn - 1)), 0);
    int mask_y = max((int)((1.0f - ph) / 2.0f * (float)(VYn - 1)), 0);

    float tx = pc[p * 7 + 0] + 4000.0f; tx = tx - 0.0f;      tx = tx - 1000.0f;
    float ty = pc[p * 7 + 1] + 4000.0f; ty = ty - (-500.0f); ty = ty - 1000.0f;
    float tz = pc[p * 7 + 2] + 1000.0f; tz = tz - 800.0f;    tz = tz - 1000.0f;
    tx = tx / 8000.0f * 252.0f;
    ty = ty / 8000.0f * 252.0f;
    tz = tz / 2000.0f * 63.0f;
    int cx = (int)rintf(tx);
    int cy = (int)rintf(ty);
    int cz = (int)rintf(tz);

    int x_start = max(-cx, 0) + mask_x;
    int x_end   = min(FXn - cx, VXn) - mask_x;
    int y_start = max(-cy, 0) + mask_y;
    int y_end   = min(FYn - cy, VYn) - mask_y;
    int z_start = max(-cz, 0);
    int z_end   = min(FZn - cz, VZn);

    const bool valid = (ix >= x_start && ix < x_end) &&
                       (iy >= y_start && iy < y_end) &&
                       (iz >= z_start && iz < z_end);

    const size_t out_base = ((((size_t)p * N_JOINTS) * VXn + ix) * VYn + iy) * VZn + iz;
    const size_t out_jstride = (size_t)VXn * VYn * VZn;

    // Wave-level early-out: x,y validity is uniform across the wave (lane=iz).
    unsigned long long mv = __ballot(valid ? 1 : 0);
    if (mv == 0ull) {
#pragma unroll
        for (int j = 0; j < N_JOINTS; ++j)
            out[out_base + j * out_jstride] = 0.0f;
        return;
    }

    const int fx = min(max(cx + ix, 0), FXn - 1);
    const int fy = min(max(cy + iy, 0), FYn - 1);
    const int fz = min(max(cz + iz, 0), FZn - 1);

    const size_t sg_base = (((size_t)fx * FYn + fy) * FZn + fz) * 2;
    const size_t sg_vstride = (size_t)FXn * FYn * FZn * 2;

    // ---- stage 1: load all sample coords (coalesced, non-temporal) ----
    vf2 g[N_VIEWS];
#pragma unroll
    for (int v = 0; v < N_VIEWS; ++v)
        g[v] = __builtin_nontemporal_load(
            (const vf2*)(sg + sg_base + (size_t)v * sg_vstride));

    // ---- stage 2: weights + 32-bit tap offsets for all views ----
    float w00[N_VIEWS], w10[N_VIEWS], w01[N_VIEWS], w11[N_VIEWS];
    unsigned off00[N_VIEWS], off10[N_VIEWS], off01[N_VIEWS], off11[N_VIEWS];
#pragma unroll
    for (int v = 0; v < N_VIEWS; ++v) {
        float px = (g[v].x + 1.0f) * 0.5f * (float)(HM_W - 1);
        float py = (g[v].y + 1.0f) * 0.5f * (float)(HM_H - 1);
        float x0f = floorf(px), y0f = floorf(py);
        float wx1 = px - x0f,  wy1 = py - y0f;
        float wx0 = 1.0f - wx1, wy0 = 1.0f - wy1;
        float x1f = x0f + 1.0f, y1f = y0f + 1.0f;
        float okx0 = (x0f >= 0.0f && x0f < (float)HM_W) ? 1.0f : 0.0f;
        float okx1 = (x1f >= 0.0f && x1f < (float)HM_W) ? 1.0f : 0.0f;
        float oky0 = (y0f >= 0.0f && y0f < (float)HM_H) ? 1.0f : 0.0f;
        float oky1 = (y1f >= 0.0f && y1f < (float)HM_H) ? 1.0f : 0.0f;
        int x0 = min(max((int)x0f, 0), HM_W - 1);
        int x1 = min(max((int)x0f + 1, 0), HM_W - 1);
        int y0 = min(max((int)y0f, 0), HM_H - 1);
        int y1 = min(max((int)y0f + 1, 0), HM_H - 1);
        w00[v] = wx0 * wy0 * okx0 * oky0;
        w10[v] = wx1 * wy0 * okx1 * oky0;
        w01[v] = wx0 * wy1 * okx0 * oky1;
        w11[v] = wx1 * wy1 * okx1 * oky1;
        unsigned vbase = (unsigned)(v * HM_H * HM_W);
        off00[v] = (vbase + (unsigned)y0 * HM_W + (unsigned)x0) * JP;
        off10[v] = (vbase + (unsigned)y0 * HM_W + (unsigned)x1) * JP;
        off01[v] = (vbase + (unsigned)y1 * HM_W + (unsigned)x0) * JP;
        off11[v] = (vbase + (unsigned)y1 * HM_W + (unsigned)x1) * JP;
    }

    // ---- stage 3: issue ALL 20 tap loads (sc0 = L1-bypass, L2-allocate) ----
#if USE_BUFLOAD
    __amdgpu_buffer_rsrc_t rs = __builtin_amdgcn_make_buffer_rsrc(
        (void*)hmT, (short)0, (int)TABLE_BYTES, 0x00020000);
    vi4 tap[N_VIEWS][4];
#pragma unroll
    for (int v = 0; v < N_VIEWS; ++v) {
        tap[v][0] = __builtin_amdgcn_raw_ptr_buffer_load_b128(rs, (int)off00[v], 0, 1);
        tap[v][1] = __builtin_amdgcn_raw_ptr_buffer_load_b128(rs, (int)off10[v], 0, 1);
        tap[v][2] = __builtin_amdgcn_raw_ptr_buffer_load_b128(rs, (int)off01[v], 0, 1);
        tap[v][3] = __builtin_amdgcn_raw_ptr_buffer_load_b128(rs, (int)off11[v], 0, 1);
    }
#else
    vu4 tap[N_VIEWS][4];
#pragma unroll
    for (int v = 0; v < N_VIEWS; ++v) {
        tap[v][0] = *(const vu4*)(hmT + off00[v]);
        tap[v][1] = *(const vu4*)(hmT + off10[v]);
        tap[v][2] = *(const vu4*)(hmT + off01[v]);
        tap[v][3] = *(const vu4*)(hmT + off11[v]);
    }
#endif

    // ---- stage 4: accumulate ----
    float acc[N_JOINTS];
#pragma unroll
    for (int j = 0; j < N_JOINTS; ++j) acc[j] = 0.0f;

#pragma unroll
    for (int v = 0; v < N_VIEWS; ++v) {
        const unsigned int* a = (const unsigned int*)&tap[v][0];
        const unsigned int* b = (const unsigned int*)&tap[v][1];
        const unsigned int* c = (const unsigned int*)&tap[v][2];
        const unsigned int* d = (const unsigned int*)&tap[v][3];
#pragma unroll
        for (int j = 0; j < N_JOINTS; ++j) {
            int word = j >> 2, sh = (j & 3) * 8;
            float fa = (float)((a[word] >> sh) & 0xffu);
            float fb = (float)((b[word] >> sh) & 0xffu);
            float fc = (float)((c[word] >> sh) & 0xffu);
            float fd = (float)((d[word] >> sh) & 0xffu);
            acc[j] += w00[v] * fa + w10[v] * fb + w01[v] * fc + w11[v] * fd;
        }
    }

    const float scale = valid ? (0.2f / 255.0f) : 0.0f;
#pragma unroll
    for (int j = 0; j < N_JOINTS; ++j) {
        float vlu = acc[j] * scale;
        vlu = fminf(fmaxf(vlu, 0.0f), 1.0f);
        out[out_base + j * out_jstride] = vlu;
    }
}

extern "C" void kernel_launch(void* const* d_in, const int* in_sizes, int n_in,
                              void* d_out, int out_size, void* d_ws, size_t ws_size,
                              hipStream_t stream) {
    const float* hm = (const float*)d_in[0];   // (5,15,128,240)
    const float* sg = (const float*)d_in[1];   // (5,253,253,64,2)
    const float* pc = (const float*)d_in[2];   // (4,7)
    float* out = (float*)d_out;

    unsigned char* T = (unsigned char*)d_ws;   // 2.46 MB

    const size_t grids_off = (size_t)PB * N_JOINTS * VXn * VYn * VZn;
    const int prep_total = T_TOTAL + G_TOTAL;
    prep_kernel<<<(prep_total + 255) / 256, 256, 0, stream>>>(hm, T, out + grids_off);

    dim3 blk(128, 1, 1);
    dim3 grd(32, 64, 4);  // (iy/2, ix, p)
    project_kernel<<<grd, blk, 0, stream>>>(T, sg, pc, out);
}

// Round 9
// 65.936 us; speedup vs baseline: 1.2429x; 1.2429x over previous
//
#include <hip/hip_runtime.h>

#define N_VIEWS 5
#define N_JOINTS 15
#define HM_H 128
#define HM_W 240
#define PB 4
#define VXn 64
#define VYn 64
#define VZn 64
#define FXn 253
#define FYn 253
#define FZn 64
#define JP 16   // joints padded to 16 -> one 16B load per tap

typedef float        vf2 __attribute__((ext_vector_type(2)));
typedef unsigned int vu4 __attribute__((ext_vector_type(4)));

#define T_TOTAL (N_VIEWS * HM_H * HM_W)     // 153600
#define G_TOTAL (3 * 4096)                  // 12288

// ---------------------------------------------------------------------------
// Kernel 1: transpose+quantize heatmaps (V,J,H,W) f32 -> (V,H,W,16) u8,
// with the constant grids output fused into trailing blocks.
// ---------------------------------------------------------------------------
__global__ void prep_kernel(const float* __restrict__ hm,
                            unsigned char* __restrict__ T,
                            float* __restrict__ gout) {
    int t = blockIdx.x * blockDim.x + threadIdx.x;
    if (t < T_TOTAL) {
        int x = t % HM_W;
        int vy = t / HM_W;
        int y = vy % HM_H;
        int v = vy / HM_H;
        unsigned int w[4] = {0u, 0u, 0u, 0u};
#pragma unroll
        for (int j = 0; j < N_JOINTS; ++j) {
            float val = hm[(((size_t)v * N_JOINTS + j) * HM_H + y) * HM_W + x];
            float q = rintf(val * 255.0f);
            q = fminf(fmaxf(q, 0.0f), 255.0f);
            w[j >> 2] |= ((unsigned int)q) << ((j & 3) * 8);
        }
        vu4* dst = (vu4*)(T + (size_t)t * JP);
        vu4 o; o.x = w[0]; o.y = w[1]; o.z = w[2]; o.w = w[3];
        *dst = o;
    } else {
        int u = t - T_TOTAL;
        if (u >= G_TOTAL) return;
        int g = u / 4096;
        int idx = u % 4096;
        int a = idx / 64;
        int b = idx % 64;
        const float step = 2000.0f / 63.0f;
        float va = -1000.0f + (float)a * step;
        float vb = -1000.0f + (float)b * step;
        float o0, o1;
        if (g == 0)      { o0 = va + 0.0f;      o1 = vb + (-500.0f); }
        else if (g == 1) { o0 = va + 0.0f;      o1 = vb + 800.0f;    }
        else             { o0 = va + (-500.0f); o1 = vb + 800.0f;    }
        gout[(size_t)u * 2 + 0] = o0;
        gout[(size_t)u * 2 + 1] = o1;
    }
}

// ---------------------------------------------------------------------------
// Kernel 2: main projection — byte-identical to the round-3 best (63.4 us):
// block = 128 (2 waves: lane = iz), grid = (32, 64, 4), plain load/store
// semantics everywhere, all 20 tap loads staged.
// ---------------------------------------------------------------------------
__global__ __launch_bounds__(128) void project_kernel(
    const unsigned char* __restrict__ hmT, // (V,H,W,16) u8, 2.46 MB
    const float* __restrict__ sg,          // (V,FX,FY,FZ,2)
    const float* __restrict__ pc,          // (P,7)
    float* __restrict__ out)               // (P,J,VX,VY,VZ)
{
    const int iz = threadIdx.x & 63;                        // 0..63
    const int iy = blockIdx.x * 2 + (threadIdx.x >> 6);     // 0..63
    const int ix = blockIdx.y;                              // 0..63
    const int p  = blockIdx.z;                              // 0..3

    // ---- per-proposal scalars (wave-uniform) ----
    const float pw = pc[p * 7 + 5];
    const float ph = pc[p * 7 + 6];
    int mask_x = max((int)((1.0f - pw) / 2.0f * (float)(VXn - 1)), 0);
    int mask_y = max((int)((1.0f - ph) / 2.0f * (float)(VYn - 1)), 0);

    float tx = pc[p * 7 + 0] + 4000.0f; tx = tx - 0.0f;      tx = tx - 1000.0f;
    float ty = pc[p * 7 + 1] + 4000.0f; ty = ty - (-500.0f); ty = ty - 1000.0f;
    float tz = pc[p * 7 + 2] + 1000.0f; tz = tz - 800.0f;    tz = tz - 1000.0f;
    tx = tx / 8000.0f * 252.0f;
    ty = ty / 8000.0f * 252.0f;
    tz = tz / 2000.0f * 63.0f;
    int cx = (int)rintf(tx);
    int cy = (int)rintf(ty);
    int cz = (int)rintf(tz);

    int x_start = max(-cx, 0) + mask_x;
    int x_end   = min(FXn - cx, VXn) - mask_x;
    int y_start = max(-cy, 0) + mask_y;
    int y_end   = min(FYn - cy, VYn) - mask_y;
    int z_start = max(-cz, 0);
    int z_end   = min(FZn - cz, VZn);

    const bool valid = (ix >= x_start && ix < x_end) &&
                       (iy >= y_start && iy < y_end) &&
                       (iz >= z_start && iz < z_end);

    const size_t out_base = ((((size_t)p * N_JOINTS) * VXn + ix) * VYn + iy) * VZn + iz;
    const size_t out_jstride = (size_t)VXn * VYn * VZn;

    // Wave-level early-out: x,y validity is uniform across the wave (lane=iz).
    unsigned long long mv = __ballot(valid ? 1 : 0);
    if (mv == 0ull) {
#pragma unroll
        for (int j = 0; j < N_JOINTS; ++j)
            out[out_base + j * out_jstride] = 0.0f;
        return;
    }

    const int fx = min(max(cx + ix, 0), FXn - 1);
    const int fy = min(max(cy + iy, 0), FYn - 1);
    const int fz = min(max(cz + iz, 0), FZn - 1);

    const size_t sg_base = (((size_t)fx * FYn + fy) * FZn + fz) * 2;
    const size_t sg_vstride = (size_t)FXn * FYn * FZn * 2;

    // ---- stage 1: load all sample coords (coalesced) ----
    vf2 g[N_VIEWS];
#pragma unroll
    for (int v = 0; v < N_VIEWS; ++v)
        g[v] = *(const vf2*)(sg + sg_base + (size_t)v * sg_vstride);

    float acc[N_JOINTS];
#pragma unroll
    for (int j = 0; j < N_JOINTS; ++j) acc[j] = 0.0f;

    // ---- stage 2: compute weights + issue ALL 20 tap loads ----
    float w00[N_VIEWS], w10[N_VIEWS], w01[N_VIEWS], w11[N_VIEWS];
    vu4 tap[N_VIEWS][4];
#pragma unroll
    for (int v = 0; v < N_VIEWS; ++v) {
        float px = (g[v].x + 1.0f) * 0.5f * (float)(HM_W - 1);
        float py = (g[v].y + 1.0f) * 0.5f * (float)(HM_H - 1);
        float x0f = floorf(px), y0f = floorf(py);
        float wx1 = px - x0f,  wy1 = py - y0f;
        float wx0 = 1.0f - wx1, wy0 = 1.0f - wy1;
        float x1f = x0f + 1.0f, y1f = y0f + 1.0f;
        float okx0 = (x0f >= 0.0f && x0f < (float)HM_W) ? 1.0f : 0.0f;
        float okx1 = (x1f >= 0.0f && x1f < (float)HM_W) ? 1.0f : 0.0f;
        float oky0 = (y0f >= 0.0f && y0f < (float)HM_H) ? 1.0f : 0.0f;
        float oky1 = (y1f >= 0.0f && y1f < (float)HM_H) ? 1.0f : 0.0f;
        int x0 = min(max((int)x0f, 0), HM_W - 1);
        int x1 = min(max((int)x0f + 1, 0), HM_W - 1);
        int y0 = min(max((int)y0f, 0), HM_H - 1);
        int y1 = min(max((int)y0f + 1, 0), HM_H - 1);
        w00[v] = wx0 * wy0 * okx0 * oky0;
        w10[v] = wx1 * wy0 * okx1 * oky0;
        w01[v] = wx0 * wy1 * okx0 * oky1;
        w11[v] = wx1 * wy1 * okx1 * oky1;
        unsigned vbase = (unsigned)(v * HM_H * HM_W);
        const unsigned char* base = hmT;
        tap[v][0] = *(const vu4*)(base + (size_t)(vbase + (unsigned)y0 * HM_W + (unsigned)x0) * JP);
        tap[v][1] = *(const vu4*)(base + (size_t)(vbase + (unsigned)y0 * HM_W + (unsigned)x1) * JP);
        tap[v][2] = *(const vu4*)(base + (size_t)(vbase + (unsigned)y1 * HM_W + (unsigned)x0) * JP);
        tap[v][3] = *(const vu4*)(base + (size_t)(vbase + (unsigned)y1 * HM_W + (unsigned)x1) * JP);
    }

    // ---- stage 3: accumulate ----
#pragma unroll
    for (int v = 0; v < N_VIEWS; ++v) {
        const unsigned int* a = (const unsigned int*)&tap[v][0];
        const unsigned int* bb = (const unsigned int*)&tap[v][1];
        const unsigned int* c = (const unsigned int*)&tap[v][2];
        const unsigned int* d = (const unsigned int*)&tap[v][3];
#pragma unroll
        for (int j = 0; j < N_JOINTS; ++j) {
            int word = j >> 2, sh = (j & 3) * 8;
            float fa = (float)((a[word] >> sh) & 0xffu);
            float fb = (float)((bb[word] >> sh) & 0xffu);
            float fc = (float)((c[word] >> sh) & 0xffu);
            float fd = (float)((d[word] >> sh) & 0xffu);
            acc[j] += w00[v] * fa + w10[v] * fb + w01[v] * fc + w11[v] * fd;
        }
    }

    const float scale = valid ? (0.2f / 255.0f) : 0.0f;
#pragma unroll
    for (int j = 0; j < N_JOINTS; ++j) {
        float vlu = acc[j] * scale;
        vlu = fminf(fmaxf(vlu, 0.0f), 1.0f);
        out[out_base + j * out_jstride] = vlu;
    }
}

extern "C" void kernel_launch(void* const* d_in, const int* in_sizes, int n_in,
                              void* d_out, int out_size, void* d_ws, size_t ws_size,
                              hipStream_t stream) {
    const float* hm = (const float*)d_in[0];   // (5,15,128,240)
    const float* sg = (const float*)d_in[1];   // (5,253,253,64,2)
    const float* pc = (const float*)d_in[2];   // (4,7)
    float* out = (float*)d_out;

    unsigned char* T = (unsigned char*)d_ws;   // 2.46 MB

    const size_t grids_off = (size_t)PB * N_JOINTS * VXn * VYn * VZn;
    const int prep_total = T_TOTAL + G_TOTAL;
    prep_kernel<<<(prep_total + 255) / 256, 256, 0, stream>>>(hm, T, out + grids_off);

    dim3 blk(128, 1, 1);
    dim3 grd(32, 64, 4);  // (iy/2, ix, p)
    project_kernel<<<grd, blk, 0, stream>>>(T, sg, pc, out);
}

// Round 10
// 63.097 us; speedup vs baseline: 1.2988x; 1.0450x over previous
//
#include <hip/hip_runtime.h>

#define N_VIEWS 5
#define N_JOINTS 15
#define HM_H 128
#define HM_W 240
#define PB 4
#define VXn 64
#define VYn 64
#define VZn 64
#define FXn 253
#define FYn 253
#define FZn 64
#define JP 16  // joints padded to 16 -> 16B per tap in u8

// ---------------------------------------------------------------------------
// Kernel 1: transpose+quantize heatmaps (V,J,H,W) f32 -> (V,H,W,JP) u8.
// Values are in [0,1); q = rint(v*255), dequant error <= 0.5/255 ~ 0.002.
// ---------------------------------------------------------------------------
__global__ void transpose_hm_kernel(const float* __restrict__ hm,
                                    unsigned char* __restrict__ T) {
    int t = blockIdx.x * blockDim.x + threadIdx.x;  // over V*H*W
    const int total = N_VIEWS * HM_H * HM_W;
    if (t >= total) return;
    int x = t % HM_W;
    int vy = t / HM_W;
    int y = vy % HM_H;
    int v = vy / HM_H;
    unsigned int w[4] = {0u, 0u, 0u, 0u};
#pragma unroll
    for (int j = 0; j < N_JOINTS; ++j) {
        float val = hm[(((size_t)v * N_JOINTS + j) * HM_H + y) * HM_W + x];
        float q = rintf(val * 255.0f);
        q = fminf(fmaxf(q, 0.0f), 255.0f);
        unsigned int b = (unsigned int)q;
        w[j >> 2] |= b << ((j & 3) * 8);
    }
    uint4* dst = (uint4*)(T + (size_t)t * JP);
    *dst = make_uint4(w[0], w[1], w[2], w[3]);
}

// ---------------------------------------------------------------------------
// Kernel 2: main projection. One thread per voxel (p, ix, iy, iz).
// block = 128 (2 waves: lane = iz, wave = iy sub-row). grid = (32, 64, 4).
// All 20 tap loads issued before any accumulation for max MLP.
// ---------------------------------------------------------------------------
__global__ __launch_bounds__(128) void project_kernel(
    const unsigned char* __restrict__ hmT, // (V,H,W,JP) u8, or nullptr
    const float* __restrict__ hm,          // original (V,J,H,W) fallback
    const float* __restrict__ sg,          // (V,FX,FY,FZ,2)
    const float* __restrict__ pc,          // (P,7)
    float* __restrict__ out)               // (P,J,VX,VY,VZ)
{
    const int iz = threadIdx.x & 63;                        // 0..63
    const int iy = blockIdx.x * 2 + (threadIdx.x >> 6);     // 0..63
    const int ix = blockIdx.y;                              // 0..63
    const int p  = blockIdx.z;                              // 0..3

    // ---- per-proposal scalars (wave-uniform) ----
    const float pw = pc[p * 7 + 5];
    const float ph = pc[p * 7 + 6];
    int mask_x = max((int)((1.0f - pw) / 2.0f * (float)(VXn - 1)), 0);
    int mask_y = max((int)((1.0f - ph) / 2.0f * (float)(VYn - 1)), 0);

    float tx = pc[p * 7 + 0] + 4000.0f; tx = tx - 0.0f;      tx = tx - 1000.0f;
    float ty = pc[p * 7 + 1] + 4000.0f; ty = ty - (-500.0f); ty = ty - 1000.0f;
    float tz = pc[p * 7 + 2] + 1000.0f; tz = tz - 800.0f;    tz = tz - 1000.0f;
    tx = tx / 8000.0f * 252.0f;
    ty = ty / 8000.0f * 252.0f;
    tz = tz / 2000.0f * 63.0f;
    int cx = (int)rintf(tx);
    int cy = (int)rintf(ty);
    int cz = (int)rintf(tz);

    int x_start = max(-cx, 0) + mask_x;
    int x_end   = min(FXn - cx, VXn) - mask_x;
    int y_start = max(-cy, 0) + mask_y;
    int y_end   = min(FYn - cy, VYn) - mask_y;
    int z_start = max(-cz, 0);
    int z_end   = min(FZn - cz, VZn);

    const bool valid = (ix >= x_start && ix < x_end) &&
                       (iy >= y_start && iy < y_end) &&
                       (iz >= z_start && iz < z_end);

    const size_t out_base = ((((size_t)p * N_JOINTS) * VXn + ix) * VYn + iy) * VZn + iz;
    const size_t out_jstride = (size_t)VXn * VYn * VZn;

    // Wave-level early-out: x,y validity is uniform across the wave (lane=iz).
    unsigned long long mv = __ballot(valid ? 1 : 0);
    if (mv == 0ull) {
#pragma unroll
        for (int j = 0; j < N_JOINTS; ++j)
            out[out_base + j * out_jstride] = 0.0f;
        return;
    }

    const int fx = min(max(cx + ix, 0), FXn - 1);
    const int fy = min(max(cy + iy, 0), FYn - 1);
    const int fz = min(max(cz + iz, 0), FZn - 1);

    const size_t sg_base = (((size_t)fx * FYn + fy) * FZn + fz) * 2;
    const size_t sg_vstride = (size_t)FXn * FYn * FZn * 2;

    // ---- stage 1: load all sample coords (coalesced) ----
    float2 g[N_VIEWS];
#pragma unroll
    for (int v = 0; v < N_VIEWS; ++v)
        g[v] = *(const float2*)(sg + sg_base + (size_t)v * sg_vstride);

    float acc[N_JOINTS];
#pragma unroll
    for (int j = 0; j < N_JOINTS; ++j) acc[j] = 0.0f;

    if (hmT != nullptr) {
        // ---- stage 2: compute weights + issue ALL 20 tap loads ----
        float w00[N_VIEWS], w10[N_VIEWS], w01[N_VIEWS], w11[N_VIEWS];
        uint4 tap[N_VIEWS][4];
#pragma unroll
        for (int v = 0; v < N_VIEWS; ++v) {
            float px = (g[v].x + 1.0f) * 0.5f * (float)(HM_W - 1);
            float py = (g[v].y + 1.0f) * 0.5f * (float)(HM_H - 1);
            float x0f = floorf(px), y0f = floorf(py);
            float wx1 = px - x0f,  wy1 = py - y0f;
            float wx0 = 1.0f - wx1, wy0 = 1.0f - wy1;
            float x1f = x0f + 1.0f, y1f = y0f + 1.0f;
            float okx0 = (x0f >= 0.0f && x0f < (float)HM_W) ? 1.0f : 0.0f;
            float okx1 = (x1f >= 0.0f && x1f < (float)HM_W) ? 1.0f : 0.0f;
            float oky0 = (y0f >= 0.0f && y0f < (float)HM_H) ? 1.0f : 0.0f;
            float oky1 = (y1f >= 0.0f && y1f < (float)HM_H) ? 1.0f : 0.0f;
            int x0 = min(max((int)x0f, 0), HM_W - 1);
            int x1 = min(max((int)x0f + 1, 0), HM_W - 1);
            int y0 = min(max((int)y0f, 0), HM_H - 1);
            int y1 = min(max((int)y0f + 1, 0), HM_H - 1);
            w00[v] = wx0 * wy0 * okx0 * oky0;
            w10[v] = wx1 * wy0 * okx1 * oky0;
            w01[v] = wx0 * wy1 * okx0 * oky1;
            w11[v] = wx1 * wy1 * okx1 * oky1;
            const unsigned char* base = hmT + (size_t)v * HM_H * HM_W * JP;
            tap[v][0] = *(const uint4*)(base + ((size_t)y0 * HM_W + x0) * JP);
            tap[v][1] = *(const uint4*)(base + ((size_t)y0 * HM_W + x1) * JP);
            tap[v][2] = *(const uint4*)(base + ((size_t)y1 * HM_W + x0) * JP);
            tap[v][3] = *(const uint4*)(base + ((size_t)y1 * HM_W + x1) * JP);
        }
        // ---- stage 3: accumulate ----
#pragma unroll
        for (int v = 0; v < N_VIEWS; ++v) {
            const unsigned int* a = (const unsigned int*)&tap[v][0];
            const unsigned int* b = (const unsigned int*)&tap[v][1];
            const unsigned int* c = (const unsigned int*)&tap[v][2];
            const unsigned int* d = (const unsigned int*)&tap[v][3];
#pragma unroll
            for (int j = 0; j < N_JOINTS; ++j) {
                int word = j >> 2, sh = (j & 3) * 8;
                float fa = (float)((a[word] >> sh) & 0xffu);
                float fb = (float)((b[word] >> sh) & 0xffu);
                float fc = (float)((c[word] >> sh) & 0xffu);
                float fd = (float)((d[word] >> sh) & 0xffu);
                acc[j] += w00[v] * fa + w10[v] * fb + w01[v] * fc + w11[v] * fd;
            }
        }
        const float scale = valid ? (0.2f / 255.0f) : 0.0f;
#pragma unroll
        for (int j = 0; j < N_JOINTS; ++j) {
            float vlu = acc[j] * scale;
            vlu = fminf(fmaxf(vlu, 0.0f), 1.0f);
            out[out_base + j * out_jstride] = vlu;
        }
    } else {
        // fallback: f32 gather from original layout
#pragma unroll
        for (int v = 0; v < N_VIEWS; ++v) {
            float px = (g[v].x + 1.0f) * 0.5f * (float)(HM_W - 1);
            float py = (g[v].y + 1.0f) * 0.5f * (float)(HM_H - 1);
            float x0f = floorf(px), y0f = floorf(py);
            float wx1 = px - x0f,  wy1 = py - y0f;
            float wx0 = 1.0f - wx1, wy0 = 1.0f - wy1;
            float x1f = x0f + 1.0f, y1f = y0f + 1.0f;
            float okx0 = (x0f >= 0.0f && x0f < (float)HM_W) ? 1.0f : 0.0f;
            float okx1 = (x1f >= 0.0f && x1f < (float)HM_W) ? 1.0f : 0.0f;
            float oky0 = (y0f >= 0.0f && y0f < (float)HM_H) ? 1.0f : 0.0f;
            float oky1 = (y1f >= 0.0f && y1f < (float)HM_H) ? 1.0f : 0.0f;
            int x0 = min(max((int)x0f, 0), HM_W - 1);
            int x1 = min(max((int)x0f + 1, 0), HM_W - 1);
            int y0 = min(max((int)y0f, 0), HM_H - 1);
            int y1 = min(max((int)y0f + 1, 0), HM_H - 1);
            float w00 = wx0 * wy0 * okx0 * oky0;
            float w10 = wx1 * wy0 * okx1 * oky0;
            float w01 = wx0 * wy1 * okx0 * oky1;
            float w11 = wx1 * wy1 * okx1 * oky1;
            const size_t b00 = ((size_t)v * N_JOINTS * HM_H + y0) * HM_W + x0;
            const size_t b10 = ((size_t)v * N_JOINTS * HM_H + y0) * HM_W + x1;
            const size_t b01 = ((size_t)v * N_JOINTS * HM_H + y1) * HM_W + x0;
            const size_t b11 = ((size_t)v * N_JOINTS * HM_H + y1) * HM_W + x1;
            const size_t js = (size_t)HM_H * HM_W;
#pragma unroll
            for (int j = 0; j < N_JOINTS; ++j)
                acc[j] += w00 * hm[b00 + j * js] + w10 * hm[b10 + j * js] +
                          w01 * hm[b01 + j * js] + w11 * hm[b11 + j * js];
        }
        const float scale = valid ? 0.2f : 0.0f;
#pragma unroll
        for (int j = 0; j < N_JOINTS; ++j) {
            float vlu = acc[j] * scale;
            vlu = fminf(fmaxf(vlu, 0.0f), 1.0f);
            out[out_base + j * out_jstride] = vlu;
        }
    }
}

// ---------------------------------------------------------------------------
// Kernel 3: the constant grids output (3, 4096, 2).
// ---------------------------------------------------------------------------
__global__ void grids_kernel(float* __restrict__ out) {
    int t = blockIdx.x * blockDim.x + threadIdx.x;
    if (t >= 3 * 4096) return;
    int g = t / 4096;
    int idx = t % 4096;
    int a = idx / 64;
    int b = idx % 64;
    const float step = 2000.0f / 63.0f;
    float va = -1000.0f + (float)a * step;
    float vb = -1000.0f + (float)b * step;
    float o0, o1;
    if (g == 0)      { o0 = va + 0.0f;      o1 = vb + (-500.0f); }
    else if (g == 1) { o0 = va + 0.0f;      o1 = vb + 800.0f;    }
    else             { o0 = va + (-500.0f); o1 = vb + 800.0f;    }
    out[(size_t)t * 2 + 0] = o0;
    out[(size_t)t * 2 + 1] = o1;
}

extern "C" void kernel_launch(void* const* d_in, const int* in_sizes, int n_in,
                              void* d_out, int out_size, void* d_ws, size_t ws_size,
                              hipStream_t stream) {
    const float* hm = (const float*)d_in[0];   // (5,15,128,240)
    const float* sg = (const float*)d_in[1];   // (5,253,253,64,2)
    const float* pc = (const float*)d_in[2];   // (4,7)
    float* out = (float*)d_out;

    const size_t needT = (size_t)N_VIEWS * HM_H * HM_W * JP;  // u8
    const bool useT = (ws_size >= needT);
    unsigned char* T = (unsigned char*)d_ws;

    if (useT) {
        const int total = N_VIEWS * HM_H * HM_W;
        transpose_hm_kernel<<<(total + 255) / 256, 256, 0, stream>>>(hm, T);
    }

    dim3 blk(128, 1, 1);
    dim3 grd(32, 64, 4);  // (iy/2, ix, p)
    project_kernel<<<grd, blk, 0, stream>>>(useT ? T : nullptr, hm, sg, pc, out);

    const size_t grids_off = (size_t)PB * N_JOINTS * VXn * VYn * VZn;
    grids_kernel<<<(3 * 4096 + 255) / 256, 256, 0, stream>>>(out + grids_off);
}